// Round 4
// baseline (346.141 us; speedup 1.0000x reference)
//
#include <hip/hip_runtime.h>
#include <stdint.h>

using s16x8 = __attribute__((ext_vector_type(8))) short;
using u16x8 = __attribute__((ext_vector_type(8))) unsigned short;
using f32x4 = __attribute__((ext_vector_type(4))) float;

__device__ __forceinline__ unsigned short f2bf(float f) {
    union { float f; uint32_t u; } v; v.f = f;
    uint32_t u = (v.u + 0x7FFFu + ((v.u >> 16) & 1u)) >> 16;
    return (unsigned short)u;
}

__device__ __forceinline__ f32x4 zero4() { f32x4 z = {0.f, 0.f, 0.f, 0.f}; return z; }

// async global->LDS, 16B per lane. LDS dest must be wave-uniform base + lane*16.
__device__ __forceinline__ void async16(const void* g, void* l) {
    __builtin_amdgcn_global_load_lds(
        reinterpret_cast<const uint32_t __attribute__((address_space(1)))*>(
            reinterpret_cast<uintptr_t>(g)),
        reinterpret_cast<uint32_t __attribute__((address_space(3)))*>(
            (uint32_t)reinterpret_cast<uintptr_t>(l)),
        16, 0, 0);
}

// ---------------- fp32 -> bf16 convert ----------------
__global__ void cvt_bf16(const float* __restrict__ in, unsigned short* __restrict__ out, int n) {
    int i = (blockIdx.x * 256 + threadIdx.x) * 8;
    if (i >= n) return;
    f32x4 a = *(const f32x4*)(in + i);
    f32x4 c = *(const f32x4*)(in + i + 4);
    u16x8 o;
    o[0] = f2bf(a[0]); o[1] = f2bf(a[1]); o[2] = f2bf(a[2]); o[3] = f2bf(a[3]);
    o[4] = f2bf(c[0]); o[5] = f2bf(c[1]); o[6] = f2bf(c[2]); o[7] = f2bf(c[3]);
    *(u16x8*)(out + i) = o;
}

#define SC 0.18033688011112042f  // 0.125 * log2(e); folded into Q at GEMM epilogue

// ---------------- QKV GEMM ----------------
// C[m,n] = sum_k X[m,k] * W[n,k] + bias[n].
// Q scatters PRE-SCALED by SC to [B,H,T,64]; K to [B,H,T,64];
// V scatters TRANSPOSED to [B*H, 64(d), T].
__global__ __launch_bounds__(256, 2)
void qkv_gemm(const unsigned short* __restrict__ A,   // [8192,1024]
              const unsigned short* __restrict__ Bw,  // [3072,1024]
              const float* __restrict__ bias,         // [3072]
              unsigned short* __restrict__ Qo,
              unsigned short* __restrict__ Ko,
              unsigned short* __restrict__ Vto) {     // [64bh][64d][2048t]
    constexpr int Kd = 1024, T = 2048, H = 16;
    __shared__ __align__(16) unsigned short As[128 * 64];
    __shared__ __align__(16) unsigned short Bs[128 * 64];
    const int tid = threadIdx.x;
    const int wave = tid >> 6, lane = tid & 63;
    const int q4 = lane >> 4, l15 = lane & 15;
    const int bm = blockIdx.y * 128, bn = blockIdx.x * 128;
    const int wm = (wave >> 1) * 64, wn = (wave & 1) * 64;

    f32x4 acc[4][4];
#pragma unroll
    for (int a = 0; a < 4; ++a)
#pragma unroll
        for (int c = 0; c < 4; ++c) acc[a][c] = zero4();

    for (int k0 = 0; k0 < Kd; k0 += 64) {
#pragma unroll
        for (int r = 0; r < 4; ++r) {
            int u = r * 256 + tid;
            int row = u >> 3, su = (u & 7) ^ (row & 7);
            async16(A + (size_t)(bm + row) * Kd + k0 + su * 8, (char*)As + u * 16);
        }
#pragma unroll
        for (int r = 0; r < 4; ++r) {
            int u = r * 256 + tid;
            int row = u >> 3, su = (u & 7) ^ (row & 7);
            async16(Bw + (size_t)(bn + row) * Kd + k0 + su * 8, (char*)Bs + u * 16);
        }
        __syncthreads();
#pragma unroll
        for (int kt = 0; kt < 2; ++kt) {
            s16x8 af[4];
#pragma unroll
            for (int mt = 0; mt < 4; ++mt) {
                int row = wm + mt * 16 + l15;
                int uu = (kt * 4 + q4) ^ (row & 7);
                af[mt] = *(const s16x8*)(As + row * 64 + uu * 8);
            }
#pragma unroll
            for (int nt = 0; nt < 4; ++nt) {
                int row = wn + nt * 16 + l15;
                int uu = (kt * 4 + q4) ^ (row & 7);
                s16x8 bfv = *(const s16x8*)(Bs + row * 64 + uu * 8);
#pragma unroll
                for (int mt = 0; mt < 4; ++mt)
                    acc[mt][nt] = __builtin_amdgcn_mfma_f32_16x16x32_bf16(af[mt], bfv, acc[mt][nt], 0, 0, 0);
            }
        }
        __syncthreads();
    }
#pragma unroll
    for (int nt = 0; nt < 4; ++nt) {
        int n = bn + wn + nt * 16 + l15;
        float bv = bias[n];
        int which = n >> 10, h = (n >> 6) & (H - 1), d = n & 63;
        if (which == 2) {
#pragma unroll
            for (int mt = 0; mt < 4; ++mt)
#pragma unroll
                for (int i = 0; i < 4; ++i) {
                    int m = bm + wm + mt * 16 + 4 * q4 + i;
                    int bb = m >> 11, t = m & (T - 1);
                    Vto[(((size_t)(bb * H + h)) * 64 + d) * T + t] = f2bf(acc[mt][nt][i] + bv);
                }
        } else {
            unsigned short* dst = (which == 0) ? Qo : Ko;
            float scl = (which == 0) ? SC : 1.0f;
#pragma unroll
            for (int mt = 0; mt < 4; ++mt)
#pragma unroll
                for (int i = 0; i < 4; ++i) {
                    int m = bm + wm + mt * 16 + 4 * q4 + i;
                    int bb = m >> 11, t = m & (T - 1);
                    dst[((((size_t)bb * H + h) * T) + t) * 64 + d] = f2bf((acc[mt][nt][i] + bv) * scl);
                }
        }
    }
}

// ---------------- flash attention ----------------
// BQ=128 (two 64-row strips; each wave owns 16 rows per strip), BKV=64.
// Fixed-max softmax in exp2 domain: p = exp2(s) with SC pre-folded into Q.
// No online max/rescale state; row-sum reduced once in the epilogue.
// LDS budget 32KB (Q-region reused for P after a-frag hoist) -> 4-5 blocks/CU.
// K/V b-frag LDS reads shared across both strips (2 MFMAs per ds_read_b128).
__global__ __launch_bounds__(256, 4)
void flash_attn(const unsigned short* __restrict__ Qg,
                const unsigned short* __restrict__ Kg,
                const unsigned short* __restrict__ Vtg,
                float* __restrict__ Out) {
    constexpr int T = 2048;
    __shared__ __align__(16) unsigned short Qs[128 * 64];  // Q tile; reused as P strips
    __shared__ __align__(16) unsigned short Ks[64 * 64];   // swizzled
    __shared__ __align__(16) unsigned short Vt[64 * 64];   // V^T, swizzled

    const int tid = threadIdx.x;
    const int wave = tid >> 6, lane = tid & 63;
    const int q4 = lane >> 4, l15 = lane & 15;
    const int bh = blockIdx.x;
    const int qt = (int)gridDim.y - 1 - (int)blockIdx.y;  // heavy blocks first
    const int b = bh >> 4, h = bh & 15;
    const int q0 = qt * 128;
    const unsigned short* qb = Qg + (size_t)bh * T * 64;
    const unsigned short* kb = Kg + (size_t)bh * T * 64;
    const unsigned short* vtb = Vtg + (size_t)bh * 64 * T;  // [d][t]

    // stage Q (128 rows, swizzled, async)
#pragma unroll
    for (int r = 0; r < 4; ++r) {
        int u = r * 256 + tid;
        int row = u >> 3, su = (u & 7) ^ (row & 7);
        async16(qb + (size_t)(q0 + row) * 64 + su * 8, (char*)Qs + u * 16);
    }
    __syncthreads();
    // hoist loop-invariant Q a-frags; Qs LDS is DEAD afterwards (becomes P space)
    s16x8 aq[2][2];
#pragma unroll
    for (int s = 0; s < 2; ++s)
#pragma unroll
        for (int kt = 0; kt < 2; ++kt) {
            int arow = s * 64 + wave * 16 + l15;
            int au = (kt * 4 + q4) ^ (arow & 7);
            aq[s][kt] = *(const s16x8*)(Qs + arow * 64 + au * 8);
        }
    // per-wave, per-strip P region inside old Qs: 16 rows x 64, XOR-swizzled units
    unsigned short* const Ps0 = Qs + (wave * 2 + 0) * 1024;
    unsigned short* const Ps1 = Qs + (wave * 2 + 1) * 1024;

    f32x4 oacc[2][4];
    float lsum[2][4];
#pragma unroll
    for (int s = 0; s < 2; ++s) {
#pragma unroll
        for (int ct = 0; ct < 4; ++ct) oacc[s][ct] = zero4();
#pragma unroll
        for (int i = 0; i < 4; ++i) lsum[s][i] = 0.f;
    }

    const int nkt = 2 * qt + 2;
    for (int j = 0; j < nkt; ++j) {
        const int c0 = j * 64;
#pragma unroll
        for (int r = 0; r < 2; ++r) {
            int u = r * 256 + tid;
            int row = u >> 3, su = (u & 7) ^ (row & 7);
            async16(kb + (size_t)(c0 + row) * 64 + su * 8, (char*)Ks + u * 16);
        }
#pragma unroll
        for (int r = 0; r < 2; ++r) {
            int u = r * 256 + tid;
            int row = u >> 3, su = (u & 7) ^ (row & 7);
            async16(vtb + (size_t)row * T + c0 + su * 8, (char*)Vt + u * 16);
        }
        __syncthreads();

        const bool alive0 = (j <= 2 * qt);
        const bool diag0 = (j == 2 * qt);
        const bool diag1 = (j == 2 * qt + 1);

        // S = Q @ K^T for both strips, sharing each K b-frag read
        f32x4 sv[2][4];
#pragma unroll
        for (int s = 0; s < 2; ++s)
#pragma unroll
            for (int t = 0; t < 4; ++t) sv[s][t] = zero4();
#pragma unroll
        for (int kt = 0; kt < 2; ++kt) {
#pragma unroll
            for (int t = 0; t < 4; ++t) {
                int brow = t * 16 + l15;
                int bu = (kt * 4 + q4) ^ (brow & 7);
                s16x8 bk = *(const s16x8*)(Ks + brow * 64 + bu * 8);
                sv[0][t] = __builtin_amdgcn_mfma_f32_16x16x32_bf16(aq[0][kt], bk, sv[0][t], 0, 0, 0);
                sv[1][t] = __builtin_amdgcn_mfma_f32_16x16x32_bf16(aq[1][kt], bk, sv[1][t], 0, 0, 0);
            }
        }

        // softmax + P store (swizzled units; per-wave region, no barrier needed)
#pragma unroll
        for (int s = 0; s < 2; ++s) {
            if (s == 0 && !alive0) continue;
            const bool dg = (s == 0) ? diag0 : diag1;
            unsigned short* const ps = (s == 0) ? Ps0 : Ps1;
#pragma unroll
            for (int t = 0; t < 4; ++t) {
#pragma unroll
                for (int i = 0; i < 4; ++i) {
                    float p = exp2f(sv[s][t][i]);
                    if (dg) {
                        int col = c0 + t * 16 + l15;
                        int row = q0 + s * 64 + wave * 16 + 4 * q4 + i;
                        if (col > row) p = 0.f;
                    }
                    lsum[s][i] += p;
                    union { float f; uint32_t u; } pb; pb.f = p;
                    int prow = 4 * q4 + i;
                    int unit = (t * 2 + (l15 >> 3)) ^ (prow & 7);
                    ps[prow * 64 + unit * 8 + (l15 & 7)] =
                        (unsigned short)((pb.u + 0x8000u) >> 16);
                }
            }
        }

        // O += P @ V, sharing each V b-frag read across strips
#pragma unroll
        for (int kt = 0; kt < 2; ++kt) {
            int pu = ((kt * 4 + q4) ^ (l15 & 7)) * 8;
            s16x8 pa0, pa1;
            if (alive0) pa0 = *(const s16x8*)(Ps0 + l15 * 64 + pu);
            pa1 = *(const s16x8*)(Ps1 + l15 * 64 + pu);
#pragma unroll
            for (int ct = 0; ct < 4; ++ct) {
                int vrow = ct * 16 + l15;
                int vu = (kt * 4 + q4) ^ (vrow & 7);
                s16x8 vv = *(const s16x8*)(Vt + vrow * 64 + vu * 8);
                if (alive0)
                    oacc[0][ct] = __builtin_amdgcn_mfma_f32_16x16x32_bf16(pa0, vv, oacc[0][ct], 0, 0, 0);
                oacc[1][ct] = __builtin_amdgcn_mfma_f32_16x16x32_bf16(pa1, vv, oacc[1][ct], 0, 0, 0);
            }
        }
        __syncthreads();  // protect Ks/Vt before next stage
    }
    // epilogue: reduce row sums (once), O / l, write [B,T,H*64]
#pragma unroll
    for (int s = 0; s < 2; ++s) {
        float inv[4];
#pragma unroll
        for (int i = 0; i < 4; ++i) {
            float rs = lsum[s][i];
            rs += __shfl_xor(rs, 1, 16);
            rs += __shfl_xor(rs, 2, 16);
            rs += __shfl_xor(rs, 4, 16);
            rs += __shfl_xor(rs, 8, 16);
            inv[i] = 1.0f / rs;
        }
#pragma unroll
        for (int ct = 0; ct < 4; ++ct)
#pragma unroll
            for (int i = 0; i < 4; ++i) {
                int row = q0 + s * 64 + wave * 16 + 4 * q4 + i;
                Out[((size_t)b * T + row) * 1024 + h * 64 + ct * 16 + l15] =
                    oacc[s][ct][i] * inv[i];
            }
    }
}

extern "C" void kernel_launch(void* const* d_in, const int* in_sizes, int n_in,
                              void* d_out, int out_size, void* d_ws, size_t ws_size,
                              hipStream_t stream) {
    const float* x = (const float*)d_in[0];     // [4,2048,1024]
    const float* W = (const float*)d_in[1];     // [3072,1024]
    const float* bias = (const float*)d_in[2];  // [3072]
    float* out = (float*)d_out;                 // [4,2048,1024]

    unsigned short* xb = (unsigned short*)d_ws;      // 8388608
    unsigned short* wb = xb + 8388608;               // 3145728
    unsigned short* qb = wb + 3145728;               // 8388608 each
    unsigned short* kb = qb + 8388608;
    unsigned short* vtb = kb + 8388608;              // V^T [bh][d][t]

    cvt_bf16<<<dim3(8388608 / 2048), dim3(256), 0, stream>>>(x, xb, 8388608);
    cvt_bf16<<<dim3(3145728 / 2048), dim3(256), 0, stream>>>(W, wb, 3145728);
    qkv_gemm<<<dim3(24, 64), dim3(256), 0, stream>>>(xb, wb, bias, qb, kb, vtb);
    flash_attn<<<dim3(64, 16), dim3(256), 0, stream>>>(qb, kb, vtb, out);
}

// Round 5
// 221.200 us; speedup vs baseline: 1.5648x; 1.5648x over previous
//
#include <hip/hip_runtime.h>
#include <stdint.h>

using s16x8 = __attribute__((ext_vector_type(8))) short;
using u16x8 = __attribute__((ext_vector_type(8))) unsigned short;
using f32x4 = __attribute__((ext_vector_type(4))) float;

__device__ __forceinline__ unsigned short f2bf(float f) {
    union { float f; uint32_t u; } v; v.f = f;
    uint32_t u = (v.u + 0x7FFFu + ((v.u >> 16) & 1u)) >> 16;
    return (unsigned short)u;
}

__device__ __forceinline__ f32x4 zero4() { f32x4 z = {0.f, 0.f, 0.f, 0.f}; return z; }

// async global->LDS, 16B per lane. LDS dest must be wave-uniform base + lane*16.
__device__ __forceinline__ void async16(const void* g, void* l) {
    __builtin_amdgcn_global_load_lds(
        reinterpret_cast<const uint32_t __attribute__((address_space(1)))*>(
            reinterpret_cast<uintptr_t>(g)),
        reinterpret_cast<uint32_t __attribute__((address_space(3)))*>(
            (uint32_t)reinterpret_cast<uintptr_t>(l)),
        16, 0, 0);
}

// ---------------- fp32 -> bf16 convert ----------------
__global__ void cvt_bf16(const float* __restrict__ in, unsigned short* __restrict__ out, int n) {
    int i = (blockIdx.x * 256 + threadIdx.x) * 8;
    if (i >= n) return;
    f32x4 a = *(const f32x4*)(in + i);
    f32x4 c = *(const f32x4*)(in + i + 4);
    u16x8 o;
    o[0] = f2bf(a[0]); o[1] = f2bf(a[1]); o[2] = f2bf(a[2]); o[3] = f2bf(a[3]);
    o[4] = f2bf(c[0]); o[5] = f2bf(c[1]); o[6] = f2bf(c[2]); o[7] = f2bf(c[3]);
    *(u16x8*)(out + i) = o;
}

#define SC 0.18033688011112042f  // 0.125 * log2(e); folded into Q at GEMM epilogue

// ---------------- QKV GEMM ----------------
// C[m,n] = sum_k X[m,k] * W[n,k] + bias[n].
// Q scatters PRE-SCALED by SC to [B,H,T,64]; K to [B,H,T,64];
// V scatters TRANSPOSED to [B*H, 64(d), T].
__global__ __launch_bounds__(256, 2)
void qkv_gemm(const unsigned short* __restrict__ A,   // [8192,1024]
              const unsigned short* __restrict__ Bw,  // [3072,1024]
              const float* __restrict__ bias,         // [3072]
              unsigned short* __restrict__ Qo,
              unsigned short* __restrict__ Ko,
              unsigned short* __restrict__ Vto) {     // [64bh][64d][2048t]
    constexpr int Kd = 1024, T = 2048, H = 16;
    __shared__ __align__(16) unsigned short As[128 * 64];
    __shared__ __align__(16) unsigned short Bs[128 * 64];
    const int tid = threadIdx.x;
    const int wave = tid >> 6, lane = tid & 63;
    const int q4 = lane >> 4, l15 = lane & 15;
    const int bm = blockIdx.y * 128, bn = blockIdx.x * 128;
    const int wm = (wave >> 1) * 64, wn = (wave & 1) * 64;

    f32x4 acc[4][4];
#pragma unroll
    for (int a = 0; a < 4; ++a)
#pragma unroll
        for (int c = 0; c < 4; ++c) acc[a][c] = zero4();

    for (int k0 = 0; k0 < Kd; k0 += 64) {
#pragma unroll
        for (int r = 0; r < 4; ++r) {
            int u = r * 256 + tid;
            int row = u >> 3, su = (u & 7) ^ (row & 7);
            async16(A + (size_t)(bm + row) * Kd + k0 + su * 8, (char*)As + u * 16);
        }
#pragma unroll
        for (int r = 0; r < 4; ++r) {
            int u = r * 256 + tid;
            int row = u >> 3, su = (u & 7) ^ (row & 7);
            async16(Bw + (size_t)(bn + row) * Kd + k0 + su * 8, (char*)Bs + u * 16);
        }
        __syncthreads();
#pragma unroll
        for (int kt = 0; kt < 2; ++kt) {
            s16x8 af[4];
#pragma unroll
            for (int mt = 0; mt < 4; ++mt) {
                int row = wm + mt * 16 + l15;
                int uu = (kt * 4 + q4) ^ (row & 7);
                af[mt] = *(const s16x8*)(As + row * 64 + uu * 8);
            }
#pragma unroll
            for (int nt = 0; nt < 4; ++nt) {
                int row = wn + nt * 16 + l15;
                int uu = (kt * 4 + q4) ^ (row & 7);
                s16x8 bfv = *(const s16x8*)(Bs + row * 64 + uu * 8);
#pragma unroll
                for (int mt = 0; mt < 4; ++mt)
                    acc[mt][nt] = __builtin_amdgcn_mfma_f32_16x16x32_bf16(af[mt], bfv, acc[mt][nt], 0, 0, 0);
            }
        }
        __syncthreads();
    }
#pragma unroll
    for (int nt = 0; nt < 4; ++nt) {
        int n = bn + wn + nt * 16 + l15;
        float bv = bias[n];
        int which = n >> 10, h = (n >> 6) & (H - 1), d = n & 63;
        if (which == 2) {
#pragma unroll
            for (int mt = 0; mt < 4; ++mt)
#pragma unroll
                for (int i = 0; i < 4; ++i) {
                    int m = bm + wm + mt * 16 + 4 * q4 + i;
                    int bb = m >> 11, t = m & (T - 1);
                    Vto[(((size_t)(bb * H + h)) * 64 + d) * T + t] = f2bf(acc[mt][nt][i] + bv);
                }
        } else {
            unsigned short* dst = (which == 0) ? Qo : Ko;
            float scl = (which == 0) ? SC : 1.0f;
#pragma unroll
            for (int mt = 0; mt < 4; ++mt)
#pragma unroll
                for (int i = 0; i < 4; ++i) {
                    int m = bm + wm + mt * 16 + 4 * q4 + i;
                    int bb = m >> 11, t = m & (T - 1);
                    dst[((((size_t)bb * H + h) * T) + t) * 64 + d] = f2bf((acc[mt][nt][i] + bv) * scl);
                }
        }
    }
}

// ---------------- flash attention ----------------
// BQ=128 (two 64-row strips; each wave owns 16 rows per strip), BKV=64.
// Fixed-max softmax in exp2 domain: p = exp2(s) with SC pre-folded into Q.
// Row-sum reduced once in the epilogue. 32KB LDS (P strips alias dead Qs).
// QK^T/softmax processed strip-SEQUENTIALLY (sv[4] live only -> no spills;
// R4's both-strips-live variant spilled to scratch: 85MB extra HBM writes).
// PV shares each V b-frag read across both strips.
__global__ __launch_bounds__(256, 3)
void flash_attn(const unsigned short* __restrict__ Qg,
                const unsigned short* __restrict__ Kg,
                const unsigned short* __restrict__ Vtg,
                float* __restrict__ Out) {
    constexpr int T = 2048;
    __shared__ __align__(16) unsigned short Qs[128 * 64];  // Q tile; reused as P strips
    __shared__ __align__(16) unsigned short Ks[64 * 64];   // swizzled
    __shared__ __align__(16) unsigned short Vt[64 * 64];   // V^T, swizzled

    const int tid = threadIdx.x;
    const int wave = tid >> 6, lane = tid & 63;
    const int q4 = lane >> 4, l15 = lane & 15;
    const int bh = blockIdx.x;
    const int qt = (int)gridDim.y - 1 - (int)blockIdx.y;  // heavy blocks first
    const int b = bh >> 4, h = bh & 15;
    const int q0 = qt * 128;
    const unsigned short* qb = Qg + (size_t)bh * T * 64;
    const unsigned short* kb = Kg + (size_t)bh * T * 64;
    const unsigned short* vtb = Vtg + (size_t)bh * 64 * T;  // [d][t]

    // stage Q (128 rows, swizzled, async)
#pragma unroll
    for (int r = 0; r < 4; ++r) {
        int u = r * 256 + tid;
        int row = u >> 3, su = (u & 7) ^ (row & 7);
        async16(qb + (size_t)(q0 + row) * 64 + su * 8, (char*)Qs + u * 16);
    }
    __syncthreads();
    // hoist loop-invariant Q a-frags; Qs LDS is DEAD afterwards (becomes P space)
    s16x8 aq[2][2];
#pragma unroll
    for (int s = 0; s < 2; ++s)
#pragma unroll
        for (int kt = 0; kt < 2; ++kt) {
            int arow = s * 64 + wave * 16 + l15;
            int au = (kt * 4 + q4) ^ (arow & 7);
            aq[s][kt] = *(const s16x8*)(Qs + arow * 64 + au * 8);
        }
    // per-wave, per-strip P region inside old Qs: 16 rows x 64, XOR-swizzled units
    unsigned short* const Ps0 = Qs + (wave * 2 + 0) * 1024;
    unsigned short* const Ps1 = Qs + (wave * 2 + 1) * 1024;

    f32x4 oacc[2][4];
    float lsum[2][4];
#pragma unroll
    for (int s = 0; s < 2; ++s) {
#pragma unroll
        for (int ct = 0; ct < 4; ++ct) oacc[s][ct] = zero4();
#pragma unroll
        for (int i = 0; i < 4; ++i) lsum[s][i] = 0.f;
    }

    const int nkt = 2 * qt + 2;
    for (int j = 0; j < nkt; ++j) {
        const int c0 = j * 64;
#pragma unroll
        for (int r = 0; r < 2; ++r) {
            int u = r * 256 + tid;
            int row = u >> 3, su = (u & 7) ^ (row & 7);
            async16(kb + (size_t)(c0 + row) * 64 + su * 8, (char*)Ks + u * 16);
        }
#pragma unroll
        for (int r = 0; r < 2; ++r) {
            int u = r * 256 + tid;
            int row = u >> 3, su = (u & 7) ^ (row & 7);
            async16(vtb + (size_t)row * T + c0 + su * 8, (char*)Vt + u * 16);
        }
        __syncthreads();

        const bool alive0 = (j <= 2 * qt);

        // strip-sequential S = Q @ K^T + softmax + P store (sv[4] live only)
#pragma unroll
        for (int s = 0; s < 2; ++s) {
            if (s == 0 && !alive0) continue;  // wave-uniform
            const bool dg = (j == 2 * qt + s);
            unsigned short* const ps = (s == 0) ? Ps0 : Ps1;

            f32x4 sv[4];
#pragma unroll
            for (int t = 0; t < 4; ++t) sv[t] = zero4();
#pragma unroll
            for (int kt = 0; kt < 2; ++kt) {
#pragma unroll
                for (int t = 0; t < 4; ++t) {
                    int brow = t * 16 + l15;
                    int bu = (kt * 4 + q4) ^ (brow & 7);
                    s16x8 bk = *(const s16x8*)(Ks + brow * 64 + bu * 8);
                    sv[t] = __builtin_amdgcn_mfma_f32_16x16x32_bf16(aq[s][kt], bk, sv[t], 0, 0, 0);
                }
            }
#pragma unroll
            for (int t = 0; t < 4; ++t) {
#pragma unroll
                for (int i = 0; i < 4; ++i) {
                    float p = exp2f(sv[t][i]);
                    if (dg) {
                        int col = c0 + t * 16 + l15;
                        int row = q0 + s * 64 + wave * 16 + 4 * q4 + i;
                        if (col > row) p = 0.f;
                    }
                    lsum[s][i] += p;
                    union { float f; uint32_t u; } pb; pb.f = p;
                    int prow = 4 * q4 + i;
                    int unit = (t * 2 + (l15 >> 3)) ^ (prow & 7);
                    ps[prow * 64 + unit * 8 + (l15 & 7)] =
                        (unsigned short)((pb.u + 0x8000u) >> 16);
                }
            }
        }

        // O += P @ V, sharing each V b-frag read across strips
#pragma unroll
        for (int kt = 0; kt < 2; ++kt) {
            int pu = ((kt * 4 + q4) ^ (l15 & 7)) * 8;
            s16x8 pa0, pa1;
            if (alive0) pa0 = *(const s16x8*)(Ps0 + l15 * 64 + pu);
            pa1 = *(const s16x8*)(Ps1 + l15 * 64 + pu);
#pragma unroll
            for (int ct = 0; ct < 4; ++ct) {
                int vrow = ct * 16 + l15;
                int vu = (kt * 4 + q4) ^ (vrow & 7);
                s16x8 vv = *(const s16x8*)(Vt + vrow * 64 + vu * 8);
                if (alive0)
                    oacc[0][ct] = __builtin_amdgcn_mfma_f32_16x16x32_bf16(pa0, vv, oacc[0][ct], 0, 0, 0);
                oacc[1][ct] = __builtin_amdgcn_mfma_f32_16x16x32_bf16(pa1, vv, oacc[1][ct], 0, 0, 0);
            }
        }
        __syncthreads();  // protect Ks/Vt before next stage
    }
    // epilogue: reduce row sums (once), O / l, write [B,T,H*64]
#pragma unroll
    for (int s = 0; s < 2; ++s) {
        float inv[4];
#pragma unroll
        for (int i = 0; i < 4; ++i) {
            float rs = lsum[s][i];
            rs += __shfl_xor(rs, 1, 16);
            rs += __shfl_xor(rs, 2, 16);
            rs += __shfl_xor(rs, 4, 16);
            rs += __shfl_xor(rs, 8, 16);
            inv[i] = 1.0f / rs;
        }
#pragma unroll
        for (int ct = 0; ct < 4; ++ct)
#pragma unroll
            for (int i = 0; i < 4; ++i) {
                int row = q0 + s * 64 + wave * 16 + 4 * q4 + i;
                Out[((size_t)b * T + row) * 1024 + h * 64 + ct * 16 + l15] =
                    oacc[s][ct][i] * inv[i];
            }
    }
}

extern "C" void kernel_launch(void* const* d_in, const int* in_sizes, int n_in,
                              void* d_out, int out_size, void* d_ws, size_t ws_size,
                              hipStream_t stream) {
    const float* x = (const float*)d_in[0];     // [4,2048,1024]
    const float* W = (const float*)d_in[1];     // [3072,1024]
    const float* bias = (const float*)d_in[2];  // [3072]
    float* out = (float*)d_out;                 // [4,2048,1024]

    unsigned short* xb = (unsigned short*)d_ws;      // 8388608
    unsigned short* wb = xb + 8388608;               // 3145728
    unsigned short* qb = wb + 3145728;               // 8388608 each
    unsigned short* kb = qb + 8388608;
    unsigned short* vtb = kb + 8388608;              // V^T [bh][d][t]

    cvt_bf16<<<dim3(8388608 / 2048), dim3(256), 0, stream>>>(x, xb, 8388608);
    cvt_bf16<<<dim3(3145728 / 2048), dim3(256), 0, stream>>>(W, wb, 3145728);
    qkv_gemm<<<dim3(24, 64), dim3(256), 0, stream>>>(xb, wb, bias, qb, kb, vtb);
    flash_attn<<<dim3(64, 16), dim3(256), 0, stream>>>(qb, kb, vtb, out);
}

// Round 6
// 205.084 us; speedup vs baseline: 1.6878x; 1.0786x over previous
//
#include <hip/hip_runtime.h>
#include <stdint.h>

using s16x8 = __attribute__((ext_vector_type(8))) short;
using u16x8 = __attribute__((ext_vector_type(8))) unsigned short;
using f32x4 = __attribute__((ext_vector_type(4))) float;
using u32x2 = __attribute__((ext_vector_type(2))) uint32_t;

__device__ __forceinline__ unsigned short f2bf(float f) {
    union { float f; uint32_t u; } v; v.f = f;
    uint32_t u = (v.u + 0x7FFFu + ((v.u >> 16) & 1u)) >> 16;
    return (unsigned short)u;
}

__device__ __forceinline__ f32x4 zero4() { f32x4 z = {0.f, 0.f, 0.f, 0.f}; return z; }

// async global->LDS, 16B per lane. LDS dest must be wave-uniform base + lane*16.
__device__ __forceinline__ void async16(const void* g, void* l) {
    __builtin_amdgcn_global_load_lds(
        reinterpret_cast<const uint32_t __attribute__((address_space(1)))*>(
            reinterpret_cast<uintptr_t>(g)),
        reinterpret_cast<uint32_t __attribute__((address_space(3)))*>(
            (uint32_t)reinterpret_cast<uintptr_t>(l)),
        16, 0, 0);
}

// ---------------- fp32 -> bf16 convert ----------------
__global__ void cvt_bf16(const float* __restrict__ in, unsigned short* __restrict__ out, int n) {
    int i = (blockIdx.x * 256 + threadIdx.x) * 8;
    if (i >= n) return;
    f32x4 a = *(const f32x4*)(in + i);
    f32x4 c = *(const f32x4*)(in + i + 4);
    u16x8 o;
    o[0] = f2bf(a[0]); o[1] = f2bf(a[1]); o[2] = f2bf(a[2]); o[3] = f2bf(a[3]);
    o[4] = f2bf(c[0]); o[5] = f2bf(c[1]); o[6] = f2bf(c[2]); o[7] = f2bf(c[3]);
    *(u16x8*)(out + i) = o;
}

#define SC 0.18033688011112042f  // 0.125 * log2(e); folded into Q at GEMM epilogue

// ---------------- QKV GEMM ----------------
// C[m,n] = sum_k X[m,k] * W[n,k] + bias[n].
// Q (pre-scaled by SC) and K scatter to [B,H,T,64].
// V blocks (n>=2048) transpose their 128x128 C-tile through LDS and write
// V^T [bh][d][t] as coalesced 256B row segments (the direct 2B scatter at
// 4KB stride was ~30x write amplification).
__global__ __launch_bounds__(256, 2)
void qkv_gemm(const unsigned short* __restrict__ A,   // [8192,1024]
              const unsigned short* __restrict__ Bw,  // [3072,1024]
              const float* __restrict__ bias,         // [3072]
              unsigned short* __restrict__ Qo,
              unsigned short* __restrict__ Ko,
              unsigned short* __restrict__ Vto) {     // [64bh][64d][2048t]
    constexpr int Kd = 1024, T = 2048, H = 16;
    __shared__ __align__(16) unsigned short smem[128 * 136];  // As+Bs; V-transpose scratch
    unsigned short* const As = smem;
    unsigned short* const Bs = smem + 128 * 64;
    const int tid = threadIdx.x;
    const int wave = tid >> 6, lane = tid & 63;
    const int q4 = lane >> 4, l15 = lane & 15;
    const int bm = blockIdx.y * 128, bn = blockIdx.x * 128;
    const int wm = (wave >> 1) * 64, wn = (wave & 1) * 64;

    f32x4 acc[4][4];
#pragma unroll
    for (int a = 0; a < 4; ++a)
#pragma unroll
        for (int c = 0; c < 4; ++c) acc[a][c] = zero4();

    for (int k0 = 0; k0 < Kd; k0 += 64) {
#pragma unroll
        for (int r = 0; r < 4; ++r) {
            int u = r * 256 + tid;
            int row = u >> 3, su = (u & 7) ^ (row & 7);
            async16(A + (size_t)(bm + row) * Kd + k0 + su * 8, (char*)As + u * 16);
        }
#pragma unroll
        for (int r = 0; r < 4; ++r) {
            int u = r * 256 + tid;
            int row = u >> 3, su = (u & 7) ^ (row & 7);
            async16(Bw + (size_t)(bn + row) * Kd + k0 + su * 8, (char*)Bs + u * 16);
        }
        __syncthreads();
#pragma unroll
        for (int kt = 0; kt < 2; ++kt) {
            s16x8 af[4];
#pragma unroll
            for (int mt = 0; mt < 4; ++mt) {
                int row = wm + mt * 16 + l15;
                int uu = (kt * 4 + q4) ^ (row & 7);
                af[mt] = *(const s16x8*)(As + row * 64 + uu * 8);
            }
#pragma unroll
            for (int nt = 0; nt < 4; ++nt) {
                int row = wn + nt * 16 + l15;
                int uu = (kt * 4 + q4) ^ (row & 7);
                s16x8 bfv = *(const s16x8*)(Bs + row * 64 + uu * 8);
#pragma unroll
                for (int mt = 0; mt < 4; ++mt)
                    acc[mt][nt] = __builtin_amdgcn_mfma_f32_16x16x32_bf16(af[mt], bfv, acc[mt][nt], 0, 0, 0);
            }
        }
        __syncthreads();
    }
    if (bn >= 2048) {
        // V: C-tile -> LDS [d_local][m_local] (stride 136, 2-way max = free)
#pragma unroll
        for (int nt = 0; nt < 4; ++nt) {
            int n = bn + wn + nt * 16 + l15;
            float bv = bias[n];
            int dl = wn + nt * 16 + l15;
#pragma unroll
            for (int mt = 0; mt < 4; ++mt)
#pragma unroll
                for (int i = 0; i < 4; ++i) {
                    int ml = wm + mt * 16 + 4 * q4 + i;
                    smem[dl * 136 + ml] = f2bf(acc[mt][nt][i] + bv);
                }
        }
        __syncthreads();
        const int bb = bm >> 11, t0 = bm & (T - 1);
#pragma unroll
        for (int rr = 0; rr < 8; ++rr) {
            int r = wave * 32 + rr * 4 + q4;      // d_local
            int d = (bn - 2048) + r;              // 0..1023
            int h = d >> 6, dd = d & 63;
            u16x8 v = *(const u16x8*)(smem + r * 136 + l15 * 8);
            *(u16x8*)(Vto + (((size_t)(bb * H + h)) * 64 + dd) * T + t0 + l15 * 8) = v;
        }
    } else {
#pragma unroll
        for (int nt = 0; nt < 4; ++nt) {
            int n = bn + wn + nt * 16 + l15;
            float bv = bias[n];
            int which = n >> 10, h = (n >> 6) & (H - 1), d = n & 63;
            unsigned short* dst = (which == 0) ? Qo : Ko;
            float scl = (which == 0) ? SC : 1.0f;
#pragma unroll
            for (int mt = 0; mt < 4; ++mt)
#pragma unroll
                for (int i = 0; i < 4; ++i) {
                    int m = bm + wm + mt * 16 + 4 * q4 + i;
                    int bb = m >> 11, t = m & (T - 1);
                    dst[((((size_t)bb * H + h) * T) + t) * 64 + d] = f2bf((acc[mt][nt][i] + bv) * scl);
                }
        }
    }
}

// ---------------- flash attention ----------------
// BQ=128 (2 strips x 16 rows/wave), BKV=64. Fixed-max softmax p=exp2(s), SC
// pre-folded into Q. S computed TRANSPOSED (S^T = K.Q^T): K frag is the MFMA
// A-operand (read once, shared across strips), and the C-layout gives each
// lane 4 consecutive kv-cols -> P stores are packed ds_write_b64 (8/wave-iter
// vs 32 b16). Row-sums are per-lane partials, reduced once in the epilogue.
// P strips alias dead Qs (LDS total 32KB).
__global__ __launch_bounds__(256, 3)
void flash_attn(const unsigned short* __restrict__ Qg,
                const unsigned short* __restrict__ Kg,
                const unsigned short* __restrict__ Vtg,
                float* __restrict__ Out) {
    constexpr int T = 2048;
    __shared__ __align__(16) unsigned short Qs[128 * 64];  // Q tile; then P strips
    __shared__ __align__(16) unsigned short Ks[64 * 64];   // swizzled
    __shared__ __align__(16) unsigned short Vt[64 * 64];   // V^T, swizzled

    const int tid = threadIdx.x;
    const int wave = tid >> 6, lane = tid & 63;
    const int q4 = lane >> 4, l15 = lane & 15;
    const int bh = blockIdx.x;
    const int qt = (int)gridDim.y - 1 - (int)blockIdx.y;  // heavy blocks first
    const int b = bh >> 4, h = bh & 15;
    const int q0 = qt * 128;
    const unsigned short* qb = Qg + (size_t)bh * T * 64;
    const unsigned short* kb = Kg + (size_t)bh * T * 64;
    const unsigned short* vtb = Vtg + (size_t)bh * 64 * T;  // [d][t]

    // stage Q (128 rows, swizzled, async)
#pragma unroll
    for (int r = 0; r < 4; ++r) {
        int u = r * 256 + tid;
        int row = u >> 3, su = (u & 7) ^ (row & 7);
        async16(qb + (size_t)(q0 + row) * 64 + su * 8, (char*)Qs + u * 16);
    }
    __syncthreads();
    // hoist Q frags (bit-identical as B-operand of S^T); Qs dead -> P space
    s16x8 aq[2][2];
#pragma unroll
    for (int s = 0; s < 2; ++s)
#pragma unroll
        for (int kt = 0; kt < 2; ++kt) {
            int arow = s * 64 + wave * 16 + l15;
            int au = (kt * 4 + q4) ^ (arow & 7);
            aq[s][kt] = *(const s16x8*)(Qs + arow * 64 + au * 8);
        }
    unsigned short* const Ps0 = Qs + (wave * 2 + 0) * 1024;  // 16x64, swizzled units
    unsigned short* const Ps1 = Qs + (wave * 2 + 1) * 1024;

    f32x4 oacc[2][4];
    float lsum[2] = {0.f, 0.f};
#pragma unroll
    for (int s = 0; s < 2; ++s)
#pragma unroll
        for (int ct = 0; ct < 4; ++ct) oacc[s][ct] = zero4();

    const int nkt = 2 * qt + 2;
    for (int j = 0; j < nkt; ++j) {
        const int c0 = j * 64;
#pragma unroll
        for (int r = 0; r < 2; ++r) {
            int u = r * 256 + tid;
            int row = u >> 3, su = (u & 7) ^ (row & 7);
            async16(kb + (size_t)(c0 + row) * 64 + su * 8, (char*)Ks + u * 16);
        }
#pragma unroll
        for (int r = 0; r < 2; ++r) {
            int u = r * 256 + tid;
            int row = u >> 3, su = (u & 7) ^ (row & 7);
            async16(vtb + (size_t)row * T + c0 + su * 8, (char*)Vt + u * 16);
        }
        __syncthreads();

        const bool alive0 = (j <= 2 * qt);

        // S^T = K @ Q^T, both strips, K A-frag shared
        f32x4 sv[2][4];
#pragma unroll
        for (int s = 0; s < 2; ++s)
#pragma unroll
            for (int t = 0; t < 4; ++t) sv[s][t] = zero4();
#pragma unroll
        for (int kt = 0; kt < 2; ++kt) {
#pragma unroll
            for (int t = 0; t < 4; ++t) {
                int krow = t * 16 + l15;
                int ku = (kt * 4 + q4) ^ (krow & 7);
                s16x8 ak = *(const s16x8*)(Ks + krow * 64 + ku * 8);
                sv[0][t] = __builtin_amdgcn_mfma_f32_16x16x32_bf16(ak, aq[0][kt], sv[0][t], 0, 0, 0);
                sv[1][t] = __builtin_amdgcn_mfma_f32_16x16x32_bf16(ak, aq[1][kt], sv[1][t], 0, 0, 0);
            }
        }

        // softmax + packed P store (lane holds kv-cols 16t+4q4+0..3, q-row l15)
#pragma unroll
        for (int s = 0; s < 2; ++s) {
            if (s == 0 && !alive0) continue;  // wave-uniform
            const bool dg = (j == 2 * qt + s);
            unsigned short* const ps = (s == 0) ? Ps0 : Ps1;
            const int qrow = q0 + s * 64 + wave * 16 + l15;
#pragma unroll
            for (int t = 0; t < 4; ++t) {
                float p0 = exp2f(sv[s][t][0]);
                float p1 = exp2f(sv[s][t][1]);
                float p2 = exp2f(sv[s][t][2]);
                float p3 = exp2f(sv[s][t][3]);
                if (dg) {
                    int col = c0 + t * 16 + 4 * q4;
                    if (col + 0 > qrow) p0 = 0.f;
                    if (col + 1 > qrow) p1 = 0.f;
                    if (col + 2 > qrow) p2 = 0.f;
                    if (col + 3 > qrow) p3 = 0.f;
                }
                lsum[s] += (p0 + p1) + (p2 + p3);
                union { float f; uint32_t u; } a0, a1, a2, a3;
                a0.f = p0; a1.f = p1; a2.f = p2; a3.f = p3;
                u32x2 w;
                w[0] = ((a0.u + 0x8000u) >> 16) | ((a1.u + 0x8000u) & 0xffff0000u);
                w[1] = ((a2.u + 0x8000u) >> 16) | ((a3.u + 0x8000u) & 0xffff0000u);
                *(u32x2*)(ps + l15 * 64 + (((2 * t + (q4 >> 1)) ^ (l15 & 7)) << 3) +
                          ((q4 & 1) << 2)) = w;
            }
        }

        // O += P @ V (P A-frag row-major re-read; V b-frag shared across strips)
#pragma unroll
        for (int kt = 0; kt < 2; ++kt) {
            int pu = ((kt * 4 + q4) ^ (l15 & 7)) * 8;
            s16x8 pa0, pa1;
            if (alive0) pa0 = *(const s16x8*)(Ps0 + l15 * 64 + pu);
            pa1 = *(const s16x8*)(Ps1 + l15 * 64 + pu);
#pragma unroll
            for (int ct = 0; ct < 4; ++ct) {
                int vrow = ct * 16 + l15;
                int vu = (kt * 4 + q4) ^ (vrow & 7);
                s16x8 vv = *(const s16x8*)(Vt + vrow * 64 + vu * 8);
                if (alive0)
                    oacc[0][ct] = __builtin_amdgcn_mfma_f32_16x16x32_bf16(pa0, vv, oacc[0][ct], 0, 0, 0);
                oacc[1][ct] = __builtin_amdgcn_mfma_f32_16x16x32_bf16(pa1, vv, oacc[1][ct], 0, 0, 0);
            }
        }
        __syncthreads();  // protect Ks/Vt before next stage
    }
    // epilogue: reduce per-lane row-sums, O / l, write [B,T,H*64]
#pragma unroll
    for (int s = 0; s < 2; ++s) {
        float rs = lsum[s];
        rs += __shfl_xor(rs, 16, 64);
        rs += __shfl_xor(rs, 32, 64);  // now: full sum of q-row l15 (strip s)
        float inv[4];
#pragma unroll
        for (int i = 0; i < 4; ++i)
            inv[i] = 1.0f / __shfl(rs, 4 * q4 + i, 64);  // sum for O-row 4q4+i
#pragma unroll
        for (int ct = 0; ct < 4; ++ct)
#pragma unroll
            for (int i = 0; i < 4; ++i) {
                int row = q0 + s * 64 + wave * 16 + 4 * q4 + i;
                Out[((size_t)b * T + row) * 1024 + h * 64 + ct * 16 + l15] =
                    oacc[s][ct][i] * inv[i];
            }
    }
}

extern "C" void kernel_launch(void* const* d_in, const int* in_sizes, int n_in,
                              void* d_out, int out_size, void* d_ws, size_t ws_size,
                              hipStream_t stream) {
    const float* x = (const float*)d_in[0];     // [4,2048,1024]
    const float* W = (const float*)d_in[1];     // [3072,1024]
    const float* bias = (const float*)d_in[2];  // [3072]
    float* out = (float*)d_out;                 // [4,2048,1024]

    unsigned short* xb = (unsigned short*)d_ws;      // 8388608
    unsigned short* wb = xb + 8388608;               // 3145728
    unsigned short* qb = wb + 3145728;               // 8388608 each
    unsigned short* kb = qb + 8388608;
    unsigned short* vtb = kb + 8388608;              // V^T [bh][d][t]

    cvt_bf16<<<dim3(8388608 / 2048), dim3(256), 0, stream>>>(x, xb, 8388608);
    cvt_bf16<<<dim3(3145728 / 2048), dim3(256), 0, stream>>>(W, wb, 3145728);
    qkv_gemm<<<dim3(24, 64), dim3(256), 0, stream>>>(xb, wb, bias, qb, kb, vtb);
    flash_attn<<<dim3(64, 16), dim3(256), 0, stream>>>(qb, kb, vtb, out);
}

// Round 7
// 200.212 us; speedup vs baseline: 1.7289x; 1.0243x over previous
//
#include <hip/hip_runtime.h>
#include <stdint.h>

using s16x8 = __attribute__((ext_vector_type(8))) short;
using u16x8 = __attribute__((ext_vector_type(8))) unsigned short;
using f32x4 = __attribute__((ext_vector_type(4))) float;
using u32x2 = __attribute__((ext_vector_type(2))) uint32_t;

__device__ __forceinline__ unsigned short f2bf(float f) {
    union { float f; uint32_t u; } v; v.f = f;
    uint32_t u = (v.u + 0x7FFFu + ((v.u >> 16) & 1u)) >> 16;
    return (unsigned short)u;
}

#if defined(__has_builtin)
#if __has_builtin(__builtin_amdgcn_cvt_pk_bf16_f32)
#define HAS_PK_BF16 1
#endif
#endif

// pack two fp32 -> two bf16 in a dword (HW packed cvt on gfx950 if available)
__device__ __forceinline__ uint32_t pk2bf(float x, float y) {
#ifdef HAS_PK_BF16
    typedef __bf16 bf16x2 __attribute__((ext_vector_type(2)));
    union { bf16x2 v; uint32_t u; } c;
    c.v = __builtin_amdgcn_cvt_pk_bf16_f32(x, y);
    return c.u;
#else
    union { float f; uint32_t u; } a, b; a.f = x; b.f = y;
    return ((a.u + 0x8000u) >> 16) | ((b.u + 0x8000u) & 0xffff0000u);
#endif
}

__device__ __forceinline__ f32x4 zero4() { f32x4 z = {0.f, 0.f, 0.f, 0.f}; return z; }

// async global->LDS, 16B per lane. LDS dest must be wave-uniform base + lane*16.
__device__ __forceinline__ void async16(const void* g, void* l) {
    __builtin_amdgcn_global_load_lds(
        reinterpret_cast<const uint32_t __attribute__((address_space(1)))*>(
            reinterpret_cast<uintptr_t>(g)),
        reinterpret_cast<uint32_t __attribute__((address_space(3)))*>(
            (uint32_t)reinterpret_cast<uintptr_t>(l)),
        16, 0, 0);
}

// ---------------- fp32 -> bf16 convert (x and W in one launch) ----------------
__global__ void cvt_bf16_2(const float* __restrict__ xa, unsigned short* __restrict__ oa, int na,
                           const float* __restrict__ xb, unsigned short* __restrict__ ob, int nb) {
    int i = (blockIdx.x * 256 + threadIdx.x) * 8;
    const float* in; unsigned short* out;
    if (i < na) { in = xa + i; out = oa + i; }
    else { int k = i - na; if (k >= nb) return; in = xb + k; out = ob + k; }
    f32x4 a = *(const f32x4*)(in);
    f32x4 c = *(const f32x4*)(in + 4);
    u16x8 o;
    o[0] = f2bf(a[0]); o[1] = f2bf(a[1]); o[2] = f2bf(a[2]); o[3] = f2bf(a[3]);
    o[4] = f2bf(c[0]); o[5] = f2bf(c[1]); o[6] = f2bf(c[2]); o[7] = f2bf(c[3]);
    *(u16x8*)(out) = o;
}

#define SC 0.18033688011112042f  // 0.125 * log2(e); folded into Q at GEMM epilogue

// ---------------- QKV GEMM ----------------
// C[m,n] = sum_k X[m,k] * W[n,k] + bias[n].
// Q (pre-scaled by SC) and K scatter to [B,H,T,64].
// V blocks (n>=2048) transpose their 128x128 C-tile through LDS and write
// V^T [bh][d][t] as coalesced 256B row segments.
__global__ __launch_bounds__(256, 2)
void qkv_gemm(const unsigned short* __restrict__ A,   // [8192,1024]
              const unsigned short* __restrict__ Bw,  // [3072,1024]
              const float* __restrict__ bias,         // [3072]
              unsigned short* __restrict__ Qo,
              unsigned short* __restrict__ Ko,
              unsigned short* __restrict__ Vto) {     // [64bh][64d][2048t]
    constexpr int Kd = 1024, T = 2048, H = 16;
    __shared__ __align__(16) unsigned short smem[128 * 136];  // As+Bs; V-transpose scratch
    unsigned short* const As = smem;
    unsigned short* const Bs = smem + 128 * 64;
    const int tid = threadIdx.x;
    const int wave = tid >> 6, lane = tid & 63;
    const int q4 = lane >> 4, l15 = lane & 15;
    const int bm = blockIdx.y * 128, bn = blockIdx.x * 128;
    const int wm = (wave >> 1) * 64, wn = (wave & 1) * 64;

    f32x4 acc[4][4];
#pragma unroll
    for (int a = 0; a < 4; ++a)
#pragma unroll
        for (int c = 0; c < 4; ++c) acc[a][c] = zero4();

    for (int k0 = 0; k0 < Kd; k0 += 64) {
#pragma unroll
        for (int r = 0; r < 4; ++r) {
            int u = r * 256 + tid;
            int row = u >> 3, su = (u & 7) ^ (row & 7);
            async16(A + (size_t)(bm + row) * Kd + k0 + su * 8, (char*)As + u * 16);
        }
#pragma unroll
        for (int r = 0; r < 4; ++r) {
            int u = r * 256 + tid;
            int row = u >> 3, su = (u & 7) ^ (row & 7);
            async16(Bw + (size_t)(bn + row) * Kd + k0 + su * 8, (char*)Bs + u * 16);
        }
        __syncthreads();
#pragma unroll
        for (int kt = 0; kt < 2; ++kt) {
            s16x8 af[4];
#pragma unroll
            for (int mt = 0; mt < 4; ++mt) {
                int row = wm + mt * 16 + l15;
                int uu = (kt * 4 + q4) ^ (row & 7);
                af[mt] = *(const s16x8*)(As + row * 64 + uu * 8);
            }
#pragma unroll
            for (int nt = 0; nt < 4; ++nt) {
                int row = wn + nt * 16 + l15;
                int uu = (kt * 4 + q4) ^ (row & 7);
                s16x8 bfv = *(const s16x8*)(Bs + row * 64 + uu * 8);
#pragma unroll
                for (int mt = 0; mt < 4; ++mt)
                    acc[mt][nt] = __builtin_amdgcn_mfma_f32_16x16x32_bf16(af[mt], bfv, acc[mt][nt], 0, 0, 0);
            }
        }
        __syncthreads();
    }
    if (bn >= 2048) {
        // V: C-tile -> LDS [d_local][m_local] (stride 136), then coalesced V^T rows
#pragma unroll
        for (int nt = 0; nt < 4; ++nt) {
            int n = bn + wn + nt * 16 + l15;
            float bv = bias[n];
            int dl = wn + nt * 16 + l15;
#pragma unroll
            for (int mt = 0; mt < 4; ++mt)
#pragma unroll
                for (int i = 0; i < 4; ++i) {
                    int ml = wm + mt * 16 + 4 * q4 + i;
                    smem[dl * 136 + ml] = f2bf(acc[mt][nt][i] + bv);
                }
        }
        __syncthreads();
        const int bb = bm >> 11, t0 = bm & (T - 1);
#pragma unroll
        for (int rr = 0; rr < 8; ++rr) {
            int r = wave * 32 + rr * 4 + q4;      // d_local
            int d = (bn - 2048) + r;              // 0..1023
            int h = d >> 6, dd = d & 63;
            u16x8 v = *(const u16x8*)(smem + r * 136 + l15 * 8);
            *(u16x8*)(Vto + (((size_t)(bb * H + h)) * 64 + dd) * T + t0 + l15 * 8) = v;
        }
    } else {
#pragma unroll
        for (int nt = 0; nt < 4; ++nt) {
            int n = bn + wn + nt * 16 + l15;
            float bv = bias[n];
            int which = n >> 10, h = (n >> 6) & (H - 1), d = n & 63;
            unsigned short* dst = (which == 0) ? Qo : Ko;
            float scl = (which == 0) ? SC : 1.0f;
#pragma unroll
            for (int mt = 0; mt < 4; ++mt)
#pragma unroll
                for (int i = 0; i < 4; ++i) {
                    int m = bm + wm + mt * 16 + 4 * q4 + i;
                    int bb = m >> 11, t = m & (T - 1);
                    dst[((((size_t)bb * H + h) * T) + t) * 64 + d] = f2bf((acc[mt][nt][i] + bv) * scl);
                }
        }
    }
}

// ---------------- flash attention ----------------
// BQ=128 (2 strips x 16 rows/wave), BKV=64, S computed transposed (S^T=K.Q^T),
// fixed-max softmax p=exp2(s) with SC pre-folded into Q.
// NEW (R7): K/V staging DOUBLE-BUFFERED — tile j+1's global_load_lds is issued
// BEFORE computing tile j, so the end-of-iter barrier's vmcnt drain waits on a
// DMA that had a full compute phase in flight (was 0 flight time = the m97
// structural stall; every pipe was <50% busy at 2 blocks/CU).
// LDS 48KB -> 3 blocks/CU.
__global__ __launch_bounds__(256, 3)
void flash_attn(const unsigned short* __restrict__ Qg,
                const unsigned short* __restrict__ Kg,
                const unsigned short* __restrict__ Vtg,
                float* __restrict__ Out) {
    constexpr int T = 2048;
    __shared__ __align__(16) unsigned short Qs[128 * 64];     // Q tile; then P strips
    __shared__ __align__(16) unsigned short Ks[2][64 * 64];   // swizzled, dbuf
    __shared__ __align__(16) unsigned short Vt[2][64 * 64];   // V^T, swizzled, dbuf

    const int tid = threadIdx.x;
    const int wave = tid >> 6, lane = tid & 63;
    const int q4 = lane >> 4, l15 = lane & 15;
    const int bh = blockIdx.x;
    const int qt = (int)gridDim.y - 1 - (int)blockIdx.y;  // heavy blocks first
    const int b = bh >> 4, h = bh & 15;
    const int q0 = qt * 128;
    const unsigned short* qb = Qg + (size_t)bh * T * 64;
    const unsigned short* kb = Kg + (size_t)bh * T * 64;
    const unsigned short* vtb = Vtg + (size_t)bh * 64 * T;  // [d][t]

    // stage Q (128 rows) + prefetch kv-tile 0 into buf 0
#pragma unroll
    for (int r = 0; r < 4; ++r) {
        int u = r * 256 + tid;
        int row = u >> 3, su = (u & 7) ^ (row & 7);
        async16(qb + (size_t)(q0 + row) * 64 + su * 8, (char*)Qs + u * 16);
    }
#pragma unroll
    for (int r = 0; r < 2; ++r) {
        int u = r * 256 + tid;
        int row = u >> 3, su = (u & 7) ^ (row & 7);
        async16(kb + (size_t)row * 64 + su * 8, (char*)Ks[0] + u * 16);
        async16(vtb + (size_t)row * T + su * 8, (char*)Vt[0] + u * 16);
    }
    __syncthreads();  // Q + tile0 ready
    // hoist Q frags (bit-identical as B-operand of S^T); Qs then becomes P space
    s16x8 aq[2][2];
#pragma unroll
    for (int s = 0; s < 2; ++s)
#pragma unroll
        for (int kt = 0; kt < 2; ++kt) {
            int arow = s * 64 + wave * 16 + l15;
            int au = (kt * 4 + q4) ^ (arow & 7);
            aq[s][kt] = *(const s16x8*)(Qs + arow * 64 + au * 8);
        }
    __syncthreads();  // all waves' hoists done before any P store overwrites Qs
    unsigned short* const Ps0 = Qs + (wave * 2 + 0) * 1024;  // 16x64, swizzled units
    unsigned short* const Ps1 = Qs + (wave * 2 + 1) * 1024;

    f32x4 oacc[2][4];
    float lsum[2] = {0.f, 0.f};
#pragma unroll
    for (int s = 0; s < 2; ++s)
#pragma unroll
        for (int ct = 0; ct < 4; ++ct) oacc[s][ct] = zero4();

    const int nkt = 2 * qt + 2;
    for (int j = 0; j < nkt; ++j) {
        // prefetch tile j+1 into the other buffer (in flight during compute of j)
        if (j + 1 < nkt) {
            const int cn = (j + 1) * 64;
            unsigned short* kd = Ks[(j + 1) & 1];
            unsigned short* vd = Vt[(j + 1) & 1];
#pragma unroll
            for (int r = 0; r < 2; ++r) {
                int u = r * 256 + tid;
                int row = u >> 3, su = (u & 7) ^ (row & 7);
                async16(kb + (size_t)(cn + row) * 64 + su * 8, (char*)kd + u * 16);
                async16(vtb + (size_t)row * T + cn + su * 8, (char*)vd + u * 16);
            }
        }
        const unsigned short* kcur = Ks[j & 1];
        const unsigned short* vcur = Vt[j & 1];
        const int c0 = j * 64;
        const bool alive0 = (j <= 2 * qt);

        // S^T = K @ Q^T, both strips, K A-frag shared
        f32x4 sv[2][4];
#pragma unroll
        for (int s = 0; s < 2; ++s)
#pragma unroll
            for (int t = 0; t < 4; ++t) sv[s][t] = zero4();
#pragma unroll
        for (int kt = 0; kt < 2; ++kt) {
#pragma unroll
            for (int t = 0; t < 4; ++t) {
                int krow = t * 16 + l15;
                int ku = (kt * 4 + q4) ^ (krow & 7);
                s16x8 ak = *(const s16x8*)(kcur + krow * 64 + ku * 8);
                sv[0][t] = __builtin_amdgcn_mfma_f32_16x16x32_bf16(ak, aq[0][kt], sv[0][t], 0, 0, 0);
                sv[1][t] = __builtin_amdgcn_mfma_f32_16x16x32_bf16(ak, aq[1][kt], sv[1][t], 0, 0, 0);
            }
        }

        // softmax + packed P store (lane holds kv-cols 16t+4q4+0..3, q-row l15)
#pragma unroll
        for (int s = 0; s < 2; ++s) {
            if (s == 0 && !alive0) continue;  // wave-uniform
            const bool dg = (j == 2 * qt + s);
            unsigned short* const ps = (s == 0) ? Ps0 : Ps1;
            const int qrow = q0 + s * 64 + wave * 16 + l15;
#pragma unroll
            for (int t = 0; t < 4; ++t) {
                float p0 = exp2f(sv[s][t][0]);
                float p1 = exp2f(sv[s][t][1]);
                float p2 = exp2f(sv[s][t][2]);
                float p3 = exp2f(sv[s][t][3]);
                if (dg) {
                    int col = c0 + t * 16 + 4 * q4;
                    if (col + 0 > qrow) p0 = 0.f;
                    if (col + 1 > qrow) p1 = 0.f;
                    if (col + 2 > qrow) p2 = 0.f;
                    if (col + 3 > qrow) p3 = 0.f;
                }
                lsum[s] += (p0 + p1) + (p2 + p3);
                u32x2 w;
                w[0] = pk2bf(p0, p1);
                w[1] = pk2bf(p2, p3);
                *(u32x2*)(ps + l15 * 64 + (((2 * t + (q4 >> 1)) ^ (l15 & 7)) << 3) +
                          ((q4 & 1) << 2)) = w;
            }
        }

        // O += P @ V (V b-frag shared across strips)
#pragma unroll
        for (int kt = 0; kt < 2; ++kt) {
            int pu = ((kt * 4 + q4) ^ (l15 & 7)) * 8;
            s16x8 pa0, pa1;
            if (alive0) pa0 = *(const s16x8*)(Ps0 + l15 * 64 + pu);
            pa1 = *(const s16x8*)(Ps1 + l15 * 64 + pu);
#pragma unroll
            for (int ct = 0; ct < 4; ++ct) {
                int vrow = ct * 16 + l15;
                int vu = (kt * 4 + q4) ^ (vrow & 7);
                s16x8 vv = *(const s16x8*)(vcur + vrow * 64 + vu * 8);
                if (alive0)
                    oacc[0][ct] = __builtin_amdgcn_mfma_f32_16x16x32_bf16(pa0, vv, oacc[0][ct], 0, 0, 0);
                oacc[1][ct] = __builtin_amdgcn_mfma_f32_16x16x32_bf16(pa1, vv, oacc[1][ct], 0, 0, 0);
            }
        }
        // waits: tile j+1 DMA (had full compute-of-j in flight) + frees buf[j&1]
        __syncthreads();
    }
    // epilogue: reduce per-lane row-sums, O / l, write [B,T,H*64]
#pragma unroll
    for (int s = 0; s < 2; ++s) {
        float rs = lsum[s];
        rs += __shfl_xor(rs, 16, 64);
        rs += __shfl_xor(rs, 32, 64);  // full sum of q-row l15 (strip s)
        float inv[4];
#pragma unroll
        for (int i = 0; i < 4; ++i)
            inv[i] = 1.0f / __shfl(rs, 4 * q4 + i, 64);  // sum for O-row 4q4+i
#pragma unroll
        for (int ct = 0; ct < 4; ++ct)
#pragma unroll
            for (int i = 0; i < 4; ++i) {
                int row = q0 + s * 64 + wave * 16 + 4 * q4 + i;
                Out[((size_t)b * T + row) * 1024 + h * 64 + ct * 16 + l15] =
                    oacc[s][ct][i] * inv[i];
            }
    }
}

extern "C" void kernel_launch(void* const* d_in, const int* in_sizes, int n_in,
                              void* d_out, int out_size, void* d_ws, size_t ws_size,
                              hipStream_t stream) {
    const float* x = (const float*)d_in[0];     // [4,2048,1024]
    const float* W = (const float*)d_in[1];     // [3072,1024]
    const float* bias = (const float*)d_in[2];  // [3072]
    float* out = (float*)d_out;                 // [4,2048,1024]

    unsigned short* xb = (unsigned short*)d_ws;      // 8388608
    unsigned short* wb = xb + 8388608;               // 3145728
    unsigned short* qb = wb + 3145728;               // 8388608 each
    unsigned short* kb = qb + 8388608;
    unsigned short* vtb = kb + 8388608;              // V^T [bh][d][t]

    cvt_bf16_2<<<dim3((8388608 + 3145728) / 2048), dim3(256), 0, stream>>>(
        x, xb, 8388608, W, wb, 3145728);
    qkv_gemm<<<dim3(24, 64), dim3(256), 0, stream>>>(xb, wb, bias, qb, kb, vtb);
    flash_attn<<<dim3(64, 16), dim3(256), 0, stream>>>(qb, kb, vtb, out);
}